// Round 3
// baseline (150.483 us; speedup 1.0000x reference)
//
#include <hip/hip_runtime.h>
#include <hip/hip_bf16.h>

typedef __bf16 bf16;
typedef __bf16 bf16x4 __attribute__((ext_vector_type(4)));
typedef __bf16 bf16x8 __attribute__((ext_vector_type(8)));
typedef float  f32x4  __attribute__((ext_vector_type(4)));

#define D_MODEL 1024
#define S_LEN   2048
#define BATCH   2
#define NH      16
#define HD      64
#define NX ((size_t)BATCH * S_LEN * D_MODEL)   // 4,194,304 elements

// async global->LDS, 16B per lane; LDS dest is wave-uniform base + lane*16
__device__ inline void gl_lds16(const bf16* g, bf16* l) {
    __builtin_amdgcn_global_load_lds(
        (const __attribute__((address_space(1))) void*)g,
        (__attribute__((address_space(3))) void*)l, 16, 0, 0);
}

// ---------------------------------------------------------------------------
// Fused prep: blocks [0,2048) convert X f32->bf16 (8 elem/thread);
// blocks [2048,2816) transpose+convert W f32 [k][n] -> Wt bf16 [z*1024+n][k].
// ---------------------------------------------------------------------------
__global__ __launch_bounds__(256) void prep(
    const float* __restrict__ x, bf16* __restrict__ xb,
    const float* __restrict__ Wq, const float* __restrict__ Wk,
    const float* __restrict__ Wv, bf16* __restrict__ Wt)
{
    __shared__ bf16 tile[64 * 72];   // [k-row][n-col], stride 72 (W path only)

    if (blockIdx.x < 2048) {
        const size_t base = ((size_t)blockIdx.x * 256 + threadIdx.x) * 8;
        const float4 a = *(const float4*)(x + base);
        const float4 b = *(const float4*)(x + base + 4);
        bf16x8 o;
        o[0] = (bf16)a.x; o[1] = (bf16)a.y; o[2] = (bf16)a.z; o[3] = (bf16)a.w;
        o[4] = (bf16)b.x; o[5] = (bf16)b.y; o[6] = (bf16)b.z; o[7] = (bf16)b.w;
        *(bf16x8*)(xb + base) = o;
        return;
    }

    const int id2 = blockIdx.x - 2048;           // 0..767
    const int z = id2 >> 8;                      // 0..2
    const float* W = (z == 0) ? Wq : (z == 1) ? Wk : Wv;
    const int k0 = ((id2 >> 4) & 15) * 64, n0 = (id2 & 15) * 64;

    const int r16 = threadIdx.x >> 4, c4 = (threadIdx.x & 15) << 2;

#pragma unroll
    for (int rr = 0; rr < 4; ++rr) {
        const int row = rr * 16 + r16;
        const float4 v = *(const float4*)(W + (size_t)(k0 + row) * D_MODEL + n0 + c4);
        bf16x4 o; o[0] = (bf16)v.x; o[1] = (bf16)v.y; o[2] = (bf16)v.z; o[3] = (bf16)v.w;
        *(bf16x4*)(tile + row * 72 + c4) = o;
    }
    __syncthreads();
#pragma unroll
    for (int rr = 0; rr < 4; ++rr) {
        const int row = rr * 16 + r16;
        bf16x4 o;
#pragma unroll
        for (int j = 0; j < 4; ++j) o[j] = tile[(c4 + j) * 72 + row];
        *(bf16x4*)(Wt + (size_t)(z * D_MODEL + n0 + row) * D_MODEL + k0 + c4) = o;
    }
}

// ---------------------------------------------------------------------------
// Deep-pipelined QKV GEMM: C = Xb @ Wt^T + bias, pre-scaled Q.
//   BM=256, BN=192, BK=32 -> 256 blocks = 1/CU. 8 waves (4M x 2N).
//   4-deep LDS circular buffer; stage tile t+3 while computing t.
//   UNIFORM 4 global_load_lds per wave per tile; counted vmcnt(8) retires
//   EXACTLY tile t's loads. Two phases per tile (12 MFMA each), stage-issue
//   at phase tops. XCD swizzle: each XCD owns an 8x4 tile rectangle.
// ---------------------------------------------------------------------------
#define GNT 32          // K tiles: 1024 / 32

__device__ __forceinline__ void stage_A(
    const bf16* __restrict__ Xb, bf16* __restrict__ sA,
    int m0, int k0, int tid, int wave)
{
    const int ci0 = tid;                 // 1024 chunks: 2 per thread
    const int r0 = ci0 >> 2, c0 = (ci0 & 3) ^ ((ci0 >> 3) & 3);
    gl_lds16(Xb + (size_t)(m0 + r0) * D_MODEL + k0 + c0 * 8, sA + wave * 512);
    const int ci1 = 512 + tid;
    const int r1 = ci1 >> 2, c1 = (ci1 & 3) ^ ((ci1 >> 3) & 3);
    gl_lds16(Xb + (size_t)(m0 + r1) * D_MODEL + k0 + c1 * 8, sA + 4096 + wave * 512);
}

__device__ __forceinline__ void stage_B(
    const bf16* __restrict__ Wt, bf16* __restrict__ sB,
    int n0, int k0, int tid, int wave, int lane)
{
    const int ci0 = tid;                 // 768 chunks: pass0 full (512) ...
    const int r0 = ci0 >> 2, c0 = (ci0 & 3) ^ ((ci0 >> 3) & 3);
    gl_lds16(Wt + (size_t)(n0 + r0) * D_MODEL + k0 + c0 * 8, sB + wave * 512);
    // ... pass1: 256 chunks as ONE half-exec load per wave (uniform vmcnt).
    const int ci1 = 512 + wave * 32 + lane;
    const int r1 = ci1 >> 2, c1 = (ci1 & 3) ^ ((ci1 >> 3) & 3);
    if (lane < 32)
        gl_lds16(Wt + (size_t)(n0 + r1) * D_MODEL + k0 + c1 * 8, sB + 4096 + wave * 256);
}

template<int VM>
__device__ __forceinline__ void gemm_tile_body(
    const bf16* __restrict__ Xb, const bf16* __restrict__ Wt,
    bf16* __restrict__ As, bf16* __restrict__ Bs,
    int m0, int n0, int t, int tid, int wave, int lane, int wm, int wn,
    int col, int pchunk, f32x4 (&acc)[4][6])
{
    // Retire this wave's 4 staging loads for tile t, then publish via barrier.
    if constexpr (VM == 8)      asm volatile("s_waitcnt vmcnt(8)" ::: "memory");
    else if constexpr (VM == 4) asm volatile("s_waitcnt vmcnt(4)" ::: "memory");
    else                        asm volatile("s_waitcnt vmcnt(0)" ::: "memory");
    asm volatile("s_barrier" ::: "memory");

    const bf16* bufA = As + (t & 3) * 8192;
    const bf16* bufB = Bs + (t & 3) * 6144;
    const bool pf = (t + 3 < GNT);
    const int k3 = (t + 3) * 32;

    // ---- phase 1: stage A(t+3), read a[0..3], b[0..2], 12 MFMA ----
    if (pf) stage_A(Xb, As + ((t + 3) & 3) * 8192, m0, k3, tid, wave);

    bf16x8 a[4], b[6];
#pragma unroll
    for (int mr = 0; mr < 4; ++mr)
        a[mr] = *(const bf16x8*)(bufA + (wm * 64 + mr * 16 + col) * 32 + pchunk * 8);
#pragma unroll
    for (int nr = 0; nr < 3; ++nr)
        b[nr] = *(const bf16x8*)(bufB + (wn * 96 + nr * 16 + col) * 32 + pchunk * 8);

    __builtin_amdgcn_s_setprio(1);
#pragma unroll
    for (int mr = 0; mr < 4; ++mr)
#pragma unroll
        for (int nr = 0; nr < 3; ++nr)
            acc[mr][nr] = __builtin_amdgcn_mfma_f32_16x16x32_bf16(a[mr], b[nr], acc[mr][nr], 0, 0, 0);
    __builtin_amdgcn_s_setprio(0);

    // ---- phase 2: stage B(t+3), read b[3..5], 12 MFMA ----
    asm volatile("s_barrier" ::: "memory");
    if (pf) stage_B(Wt, Bs + ((t + 3) & 3) * 6144, n0, k3, tid, wave, lane);
#pragma unroll
    for (int nr = 3; nr < 6; ++nr)
        b[nr] = *(const bf16x8*)(bufB + (wn * 96 + nr * 16 + col) * 32 + pchunk * 8);

    __builtin_amdgcn_s_setprio(1);
#pragma unroll
    for (int mr = 0; mr < 4; ++mr)
#pragma unroll
        for (int nr = 3; nr < 6; ++nr)
            acc[mr][nr] = __builtin_amdgcn_mfma_f32_16x16x32_bf16(a[mr], b[nr], acc[mr][nr], 0, 0, 0);
    __builtin_amdgcn_s_setprio(0);
}

__global__ __launch_bounds__(512, 2) void gemm_qkv_dp(
    const bf16* __restrict__ Xb, const bf16* __restrict__ Wt,
    const float* __restrict__ bq, const float* __restrict__ bk,
    const float* __restrict__ bv, bf16* __restrict__ QKV)
{
    extern __shared__ bf16 smem[];
    bf16* As = smem;            // 4 bufs x 8192 elems (256x32)
    bf16* Bs = smem + 32768;    // 4 bufs x 6144 elems (192x32)

    // XCD swizzle: xcd k = bid&7 gets an 8(n) x 4(m) rectangle of tiles.
    const int bid = blockIdx.x, k = bid & 7, j = bid >> 3;
    const int nx = ((k >> 2) << 3) + (j & 7);    // 0..15
    const int my = ((k & 3) << 2) + (j >> 3);    // 0..15
    const int n0 = nx * 192, m0 = my * 256;

    const int tid = threadIdx.x, wave = tid >> 6, lane = tid & 63;
    const int wm = wave >> 1, wn = wave & 1;
    const int col = lane & 15, quad = lane >> 4;
    const int pchunk = quad ^ ((col >> 1) & 3);

    f32x4 acc[4][6] = {};

    // prologue: stage tiles 0..2
    stage_A(Xb, As,         m0,  0, tid, wave);  stage_B(Wt, Bs,         n0,  0, tid, wave, lane);
    stage_A(Xb, As + 8192,  m0, 32, tid, wave);  stage_B(Wt, Bs + 6144,  n0, 32, tid, wave, lane);
    stage_A(Xb, As + 16384, m0, 64, tid, wave);  stage_B(Wt, Bs + 12288, n0, 64, tid, wave, lane);

    for (int t = 0; t < GNT - 2; ++t)
        gemm_tile_body<8>(Xb, Wt, As, Bs, m0, n0, t, tid, wave, lane, wm, wn, col, pchunk, acc);
    gemm_tile_body<4>(Xb, Wt, As, Bs, m0, n0, GNT - 2, tid, wave, lane, wm, wn, col, pchunk, acc);
    gemm_tile_body<0>(Xb, Wt, As, Bs, m0, n0, GNT - 1, tid, wave, lane, wm, wn, col, pchunk, acc);

    // epilogue: bias + (Q-only) 0.125 pre-scale, bf16 store.
#pragma unroll
    for (int nr = 0; nr < 6; ++nr) {
        const int cg = n0 + wn * 96 + nr * 16 + col;       // 0..3071
        const int z = cg >> 10, c = cg & 1023;
        const float bsv = (z == 0 ? bq : (z == 1 ? bk : bv))[c];
        const float scale = (z == 0) ? 0.125f : 1.0f;
        bf16* C = QKV + (size_t)z * NX;
#pragma unroll
        for (int mr = 0; mr < 4; ++mr)
#pragma unroll
            for (int i = 0; i < 4; ++i) {
                const int rg = m0 + wm * 64 + mr * 16 + quad * 4 + i;
                C[(size_t)rg * D_MODEL + c] = (bf16)((acc[mr][nr][i] + bsv) * scale);
            }
    }
}

// ---------------------------------------------------------------------------
// Block-sparse flash attention, 64-key chunks, NO-MAX single-pass softmax.
// K is read DIRECTLY from global into MFMA B-fragments (L2-resident after
// the XCD swizzle; all 4 waves previously re-read identical K from LDS).
// V stays double-buffered in LDS (transpose needed). kpm prefetched one
// iteration ahead. LDS 46KB -> 27.6KB => occupancy 3 -> 4+ blocks/CU.
// ---------------------------------------------------------------------------
__global__ __launch_bounds__(256, 4) void sparse_attn64(
    const bf16* __restrict__ Q, const bf16* __restrict__ Kv,
    const bf16* __restrict__ Vv, const float* __restrict__ kpm,
    float* __restrict__ out)
{
    // linear id -> (xcd k, j); pair = k*4 + (j&3); w descending in j.
    const int lid = blockIdx.x + 32 * (blockIdx.y + 16 * blockIdx.z);
    const int xk = lid & 7, j = lid >> 3;
    const int pair = xk * 4 + (j & 3);
    const int h = pair & 15, b = pair >> 4;
    const int w = 31 - (j >> 2);                  // longest windows first

    const int t = threadIdx.x, wavei = t >> 6, lane = t & 63;
    const int col = lane & 15, quad = lane >> 4;
    const int qb = 4 * w + wavei;

    __shared__ bf16 VtS[2][64 * 72];   // [d][kj]  stride 72
    __shared__ bf16 Ps[4][16 * 72];    // per-wave [qi][kj]

    const size_t qrow = ((size_t)(b * S_LEN + qb * 16 + col)) * D_MODEL + h * HD;
    const bf16x8 aq0 = *(const bf16x8*)(Q + qrow + quad * 8);
    const bf16x8 aq1 = *(const bf16x8*)(Q + qrow + 32 + quad * 8);

    f32x4 o[4] = {};
    float lacc[4] = {0.f, 0.f, 0.f, 0.f};

    const int nGlob = (w + 3) >> 2;
    const int niter = nGlob + 1;

    // V staging: thread = key pair (2p2, 2p2+1), d-range dg8..+7
    const int p2 = t & 31, dg8 = (t >> 5) << 3;
    const int key0 = 2 * p2, vg = key0 >> 4, vr = key0 & 15;

    // kb for (chunk it, group g); invalid globals clamp to kb=3 (masked later)
    auto kb_of = [&](int it, int g) -> int {
        if (it >= nGlob) return 4 * w + g;
        const int jj = 4 * it + g;
        return (jj < w) ? (4 * jj + 3) : 3;
    };

    bf16x8 kf0[4], kf1[4], rv0, rv1;
    float mnext[4], mval[4];

    {   // prologue: issue V(0), K(0), kpm(0); stage V(0) into buffer 0
        const size_t vrow = ((size_t)(b * S_LEN + kb_of(0, vg) * 16 + vr)) * D_MODEL + h * HD + dg8;
        rv0 = *(const bf16x8*)(Vv + vrow);
        rv1 = *(const bf16x8*)(Vv + vrow + D_MODEL);
#pragma unroll
        for (int g = 0; g < 4; ++g) {
            const int kb = kb_of(0, g);
            const size_t kr = ((size_t)(b * S_LEN + kb * 16 + col)) * D_MODEL + h * HD + quad * 8;
            kf0[g] = *(const bf16x8*)(Kv + kr);
            kf1[g] = *(const bf16x8*)(Kv + kr + 32);
            mnext[g] = kpm[b * S_LEN + kb * 16 + col];
        }
#pragma unroll
        for (int jj = 0; jj < 8; ++jj) {
            bf16 pr[2] = { rv0[jj], rv1[jj] };
            *(unsigned int*)(VtS[0] + (dg8 + jj) * 72 + key0) = *(unsigned int*)pr;
        }
    }

    for (int it = 0; it < niter; ++it) {
        __syncthreads();    // V staging of chunk `it` visible to all waves
        const int cur = it & 1, nxt = cur ^ 1;
        const bool more = (it + 1 < niter);

        // consume prefetched kpm for this chunk
#pragma unroll
        for (int g = 0; g < 4; ++g) mval[g] = mnext[g];

        // ---- S = Q K^T over 64 keys (K frags already in registers) ----
        f32x4 s[4];
        bool  val[4];
#pragma unroll
        for (int g = 0; g < 4; ++g) {
            if (it == nGlob) val[g] = (g <= wavei);
            else             val[g] = (4 * it + g < w);
            f32x4 z = {};
            __builtin_amdgcn_s_setprio(1);
            z = __builtin_amdgcn_mfma_f32_16x16x32_bf16(aq0, kf0[g], z, 0, 0, 0);
            s[g] = __builtin_amdgcn_mfma_f32_16x16x32_bf16(aq1, kf1[g], z, 0, 0, 0);
            __builtin_amdgcn_s_setprio(0);
        }

        if (more) {   // prefetch chunk it+1: V first (stage waits on it), then K, kpm
            const size_t vrow = ((size_t)(b * S_LEN + kb_of(it + 1, vg) * 16 + vr)) * D_MODEL + h * HD + dg8;
            rv0 = *(const bf16x8*)(Vv + vrow);
            rv1 = *(const bf16x8*)(Vv + vrow + D_MODEL);
#pragma unroll
            for (int g = 0; g < 4; ++g) {
                const int kb = kb_of(it + 1, g);
                const size_t kr = ((size_t)(b * S_LEN + kb * 16 + col)) * D_MODEL + h * HD + quad * 8;
                kf0[g] = *(const bf16x8*)(Kv + kr);
                kf1[g] = *(const bf16x8*)(Kv + kr + 32);
                mnext[g] = kpm[b * S_LEN + kb * 16 + col];
            }
        }

        // ---- p = exp(s + mask); no max, no rescale (order-free sums) ----
#pragma unroll
        for (int i = 0; i < 4; ++i) {
#pragma unroll
            for (int g = 0; g < 4; ++g) {
                const float si = val[g] ? (s[g][i] + mval[g]) : -1e30f;
                const float pv = __expf(si);
                lacc[i] += pv;
                Ps[wavei][(quad * 4 + i) * 72 + g * 16 + col] = (bf16)pv;
            }
        }

        // ---- O += P V : full K-depth 64 (wave-synchronous Ps round-trip) ----
        const bf16* Vt = VtS[cur];
        const bf16x8 aP0 = *(const bf16x8*)(Ps[wavei] + col * 72 + quad * 8);
        const bf16x8 aP1 = *(const bf16x8*)(Ps[wavei] + col * 72 + 32 + quad * 8);
        __builtin_amdgcn_s_setprio(1);
#pragma unroll
        for (int nt = 0; nt < 4; ++nt) {
            const bf16x8 b0 = *(const bf16x8*)(Vt + (nt * 16 + col) * 72 + quad * 8);
            const bf16x8 b1 = *(const bf16x8*)(Vt + (nt * 16 + col) * 72 + 32 + quad * 8);
            o[nt] = __builtin_amdgcn_mfma_f32_16x16x32_bf16(aP0, b0, o[nt], 0, 0, 0);
            o[nt] = __builtin_amdgcn_mfma_f32_16x16x32_bf16(aP1, b1, o[nt], 0, 0, 0);
        }
        __builtin_amdgcn_s_setprio(0);

        if (more) {   // stage V(it+1) into the other buffer (no barrier)
#pragma unroll
            for (int jj = 0; jj < 8; ++jj) {
                bf16 pr[2] = { rv0[jj], rv1[jj] };
                *(unsigned int*)(VtS[nxt] + (dg8 + jj) * 72 + key0) = *(unsigned int*)pr;
            }
        }
    }

    // ---- deferred row-sum reduction (once per block) ----
#pragma unroll
    for (int i = 0; i < 4; ++i) {
        float rs = lacc[i];
        rs += __shfl_xor(rs, 1);
        rs += __shfl_xor(rs, 2);
        rs += __shfl_xor(rs, 4);
        rs += __shfl_xor(rs, 8);
        const float inv = 1.0f / rs;
        const int rg = b * S_LEN + qb * 16 + quad * 4 + i;
#pragma unroll
        for (int nt = 0; nt < 4; ++nt)
            out[(size_t)rg * D_MODEL + h * HD + nt * 16 + col] = o[nt][i] * inv;
    }
}

// ---------------------------------------------------------------------------
extern "C" void kernel_launch(void* const* d_in, const int* in_sizes, int n_in,
                              void* d_out, int out_size, void* d_ws, size_t ws_size,
                              hipStream_t stream)
{
    const float* x = nullptr; const float* kpm = nullptr;
    const float* Wp[3] = {nullptr, nullptr, nullptr};
    const float* bp[3] = {nullptr, nullptr, nullptr};
    int wn = 0, bn = 0;
    for (int i = 0; i < n_in; ++i) {
        const float* p = (const float*)d_in[i];
        const long s = in_sizes[i];
        if (s == (long)NX)            x = p;
        else if (s == BATCH * S_LEN)  kpm = p;
        else if (s == D_MODEL * D_MODEL && wn < 3) Wp[wn++] = p;
        else if (s == D_MODEL && bn < 3)           bp[bn++] = p;
    }

    // ws (24 MB, proven safe): [Q | K | V] bf16.
    bf16* Qb = (bf16*)d_ws;
    bf16* Kb = Qb + NX;
    bf16* Vb = Kb + NX;
    // d_out (16 MB f32) doubles as pre-attention scratch: [Xb 8MB | Wt 6MB].
    bf16* Xb = (bf16*)d_out;
    bf16* Wt = Xb + NX;
    float* outp = (float*)d_out;

    static bool attr_done = false;
    if (!attr_done) {
        (void)hipFuncSetAttribute(reinterpret_cast<const void*>(gemm_qkv_dp),
                                  hipFuncAttributeMaxDynamicSharedMemorySize, 114688);
        attr_done = true;
    }

    prep<<<2816, 256, 0, stream>>>(x, Xb, Wp[0], Wp[1], Wp[2], Wt);

    // 256x192 tiles, XCD-rect swizzle: 256 blocks = 1 per CU. 112KB LDS.
    gemm_qkv_dp<<<dim3(256), 512, 114688, stream>>>(
        Xb, Wt, bp[0], bp[1], bp[2], Qb);

    sparse_attn64<<<dim3(S_LEN / 64, NH, BATCH), 256, 0, stream>>>(
        Qb, Kb, Vb, kpm, outp);
}

// Round 4
// 135.523 us; speedup vs baseline: 1.1104x; 1.1104x over previous
//
#include <hip/hip_runtime.h>
#include <hip/hip_bf16.h>

typedef __bf16 bf16;
typedef __bf16 bf16x4 __attribute__((ext_vector_type(4)));
typedef __bf16 bf16x8 __attribute__((ext_vector_type(8)));
typedef float  f32x4  __attribute__((ext_vector_type(4)));

#define D_MODEL 1024
#define S_LEN   2048
#define BATCH   2
#define NH      16
#define HD      64
#define NX ((size_t)BATCH * S_LEN * D_MODEL)   // 4,194,304 elements

// async global->LDS, 16B per lane; LDS dest is wave-uniform base + lane*16
__device__ inline void gl_lds16(const bf16* g, bf16* l) {
    __builtin_amdgcn_global_load_lds(
        (const __attribute__((address_space(1))) void*)g,
        (__attribute__((address_space(3))) void*)l, 16, 0, 0);
}

// ---------------------------------------------------------------------------
// Fused prep: blocks [0,2048) convert X f32->bf16 (8 elem/thread);
// blocks [2048,2816) transpose+convert W f32 [k][n] -> Wt bf16 [z*1024+n][k].
// ---------------------------------------------------------------------------
__global__ __launch_bounds__(256) void prep(
    const float* __restrict__ x, bf16* __restrict__ xb,
    const float* __restrict__ Wq, const float* __restrict__ Wk,
    const float* __restrict__ Wv, bf16* __restrict__ Wt)
{
    __shared__ bf16 tile[64 * 72];   // [k-row][n-col], stride 72 (W path only)

    if (blockIdx.x < 2048) {
        const size_t base = ((size_t)blockIdx.x * 256 + threadIdx.x) * 8;
        const float4 a = *(const float4*)(x + base);
        const float4 b = *(const float4*)(x + base + 4);
        bf16x8 o;
        o[0] = (bf16)a.x; o[1] = (bf16)a.y; o[2] = (bf16)a.z; o[3] = (bf16)a.w;
        o[4] = (bf16)b.x; o[5] = (bf16)b.y; o[6] = (bf16)b.z; o[7] = (bf16)b.w;
        *(bf16x8*)(xb + base) = o;
        return;
    }

    const int id2 = blockIdx.x - 2048;           // 0..767
    const int z = id2 >> 8;                      // 0..2
    const float* W = (z == 0) ? Wq : (z == 1) ? Wk : Wv;
    const int k0 = ((id2 >> 4) & 15) * 64, n0 = (id2 & 15) * 64;

    const int r16 = threadIdx.x >> 4, c4 = (threadIdx.x & 15) << 2;

#pragma unroll
    for (int rr = 0; rr < 4; ++rr) {
        const int row = rr * 16 + r16;
        const float4 v = *(const float4*)(W + (size_t)(k0 + row) * D_MODEL + n0 + c4);
        bf16x4 o; o[0] = (bf16)v.x; o[1] = (bf16)v.y; o[2] = (bf16)v.z; o[3] = (bf16)v.w;
        *(bf16x4*)(tile + row * 72 + c4) = o;
    }
    __syncthreads();
#pragma unroll
    for (int rr = 0; rr < 4; ++rr) {
        const int row = rr * 16 + r16;
        bf16x4 o;
#pragma unroll
        for (int j = 0; j < 4; ++j) o[j] = tile[(c4 + j) * 72 + row];
        *(bf16x4*)(Wt + (size_t)(z * D_MODEL + n0 + row) * D_MODEL + k0 + c4) = o;
    }
}

// ---------------------------------------------------------------------------
// Deep-pipelined QKV GEMM: C = Xb @ Wt^T + bias, pre-scaled Q.
//   BM=256, BN=192, BK=32 -> 256 blocks = 1/CU. 8 waves (4M x 2N).
//   4-deep LDS circular buffer; stage tile t+3 while computing t.
//   UNIFORM 4 global_load_lds per wave per tile; counted vmcnt(8) retires
//   EXACTLY tile t's loads. Two phases per tile (12 MFMA each), stage-issue
//   at phase tops. XCD swizzle: each XCD owns an 8x4 tile rectangle.
// ---------------------------------------------------------------------------
#define GNT 32          // K tiles: 1024 / 32

__device__ __forceinline__ void stage_A(
    const bf16* __restrict__ Xb, bf16* __restrict__ sA,
    int m0, int k0, int tid, int wave)
{
    const int ci0 = tid;                 // 1024 chunks: 2 per thread
    const int r0 = ci0 >> 2, c0 = (ci0 & 3) ^ ((ci0 >> 3) & 3);
    gl_lds16(Xb + (size_t)(m0 + r0) * D_MODEL + k0 + c0 * 8, sA + wave * 512);
    const int ci1 = 512 + tid;
    const int r1 = ci1 >> 2, c1 = (ci1 & 3) ^ ((ci1 >> 3) & 3);
    gl_lds16(Xb + (size_t)(m0 + r1) * D_MODEL + k0 + c1 * 8, sA + 4096 + wave * 512);
}

__device__ __forceinline__ void stage_B(
    const bf16* __restrict__ Wt, bf16* __restrict__ sB,
    int n0, int k0, int tid, int wave, int lane)
{
    const int ci0 = tid;                 // 768 chunks: pass0 full (512) ...
    const int r0 = ci0 >> 2, c0 = (ci0 & 3) ^ ((ci0 >> 3) & 3);
    gl_lds16(Wt + (size_t)(n0 + r0) * D_MODEL + k0 + c0 * 8, sB + wave * 512);
    // ... pass1: 256 chunks as ONE half-exec load per wave (uniform vmcnt).
    const int ci1 = 512 + wave * 32 + lane;
    const int r1 = ci1 >> 2, c1 = (ci1 & 3) ^ ((ci1 >> 3) & 3);
    if (lane < 32)
        gl_lds16(Wt + (size_t)(n0 + r1) * D_MODEL + k0 + c1 * 8, sB + 4096 + wave * 256);
}

template<int VM>
__device__ __forceinline__ void gemm_tile_body(
    const bf16* __restrict__ Xb, const bf16* __restrict__ Wt,
    bf16* __restrict__ As, bf16* __restrict__ Bs,
    int m0, int n0, int t, int tid, int wave, int lane, int wm, int wn,
    int col, int pchunk, f32x4 (&acc)[4][6])
{
    // Retire this wave's 4 staging loads for tile t, then publish via barrier.
    if constexpr (VM == 8)      asm volatile("s_waitcnt vmcnt(8)" ::: "memory");
    else if constexpr (VM == 4) asm volatile("s_waitcnt vmcnt(4)" ::: "memory");
    else                        asm volatile("s_waitcnt vmcnt(0)" ::: "memory");
    asm volatile("s_barrier" ::: "memory");

    const bf16* bufA = As + (t & 3) * 8192;
    const bf16* bufB = Bs + (t & 3) * 6144;
    const bool pf = (t + 3 < GNT);
    const int k3 = (t + 3) * 32;

    // ---- phase 1: stage A(t+3), read a[0..3], b[0..2], 12 MFMA ----
    if (pf) stage_A(Xb, As + ((t + 3) & 3) * 8192, m0, k3, tid, wave);

    bf16x8 a[4], b[6];
#pragma unroll
    for (int mr = 0; mr < 4; ++mr)
        a[mr] = *(const bf16x8*)(bufA + (wm * 64 + mr * 16 + col) * 32 + pchunk * 8);
#pragma unroll
    for (int nr = 0; nr < 3; ++nr)
        b[nr] = *(const bf16x8*)(bufB + (wn * 96 + nr * 16 + col) * 32 + pchunk * 8);

    __builtin_amdgcn_s_setprio(1);
#pragma unroll
    for (int mr = 0; mr < 4; ++mr)
#pragma unroll
        for (int nr = 0; nr < 3; ++nr)
            acc[mr][nr] = __builtin_amdgcn_mfma_f32_16x16x32_bf16(a[mr], b[nr], acc[mr][nr], 0, 0, 0);
    __builtin_amdgcn_s_setprio(0);

    // ---- phase 2: stage B(t+3), read b[3..5], 12 MFMA ----
    asm volatile("s_barrier" ::: "memory");
    if (pf) stage_B(Wt, Bs + ((t + 3) & 3) * 6144, n0, k3, tid, wave, lane);
#pragma unroll
    for (int nr = 3; nr < 6; ++nr)
        b[nr] = *(const bf16x8*)(bufB + (wn * 96 + nr * 16 + col) * 32 + pchunk * 8);

    __builtin_amdgcn_s_setprio(1);
#pragma unroll
    for (int mr = 0; mr < 4; ++mr)
#pragma unroll
        for (int nr = 3; nr < 6; ++nr)
            acc[mr][nr] = __builtin_amdgcn_mfma_f32_16x16x32_bf16(a[mr], b[nr], acc[mr][nr], 0, 0, 0);
    __builtin_amdgcn_s_setprio(0);
}

__global__ __launch_bounds__(512, 2) void gemm_qkv_dp(
    const bf16* __restrict__ Xb, const bf16* __restrict__ Wt,
    const float* __restrict__ bq, const float* __restrict__ bk,
    const float* __restrict__ bv, bf16* __restrict__ QKV)
{
    extern __shared__ bf16 smem[];
    bf16* As = smem;            // 4 bufs x 8192 elems (256x32)
    bf16* Bs = smem + 32768;    // 4 bufs x 6144 elems (192x32)

    // XCD swizzle: xcd k = bid&7 gets an 8(n) x 4(m) rectangle of tiles.
    const int bid = blockIdx.x, k = bid & 7, j = bid >> 3;
    const int nx = ((k >> 2) << 3) + (j & 7);    // 0..15
    const int my = ((k & 3) << 2) + (j >> 3);    // 0..15
    const int n0 = nx * 192, m0 = my * 256;

    const int tid = threadIdx.x, wave = tid >> 6, lane = tid & 63;
    const int wm = wave >> 1, wn = wave & 1;
    const int col = lane & 15, quad = lane >> 4;
    const int pchunk = quad ^ ((col >> 1) & 3);

    f32x4 acc[4][6] = {};

    // prologue: stage tiles 0..2
    stage_A(Xb, As,         m0,  0, tid, wave);  stage_B(Wt, Bs,         n0,  0, tid, wave, lane);
    stage_A(Xb, As + 8192,  m0, 32, tid, wave);  stage_B(Wt, Bs + 6144,  n0, 32, tid, wave, lane);
    stage_A(Xb, As + 16384, m0, 64, tid, wave);  stage_B(Wt, Bs + 12288, n0, 64, tid, wave, lane);

    for (int t = 0; t < GNT - 2; ++t)
        gemm_tile_body<8>(Xb, Wt, As, Bs, m0, n0, t, tid, wave, lane, wm, wn, col, pchunk, acc);
    gemm_tile_body<4>(Xb, Wt, As, Bs, m0, n0, GNT - 2, tid, wave, lane, wm, wn, col, pchunk, acc);
    gemm_tile_body<0>(Xb, Wt, As, Bs, m0, n0, GNT - 1, tid, wave, lane, wm, wn, col, pchunk, acc);

    // epilogue: bias + (Q-only) 0.125 pre-scale, bf16 store.
#pragma unroll
    for (int nr = 0; nr < 6; ++nr) {
        const int cg = n0 + wn * 96 + nr * 16 + col;       // 0..3071
        const int z = cg >> 10, c = cg & 1023;
        const float bsv = (z == 0 ? bq : (z == 1 ? bk : bv))[c];
        const float scale = (z == 0) ? 0.125f : 1.0f;
        bf16* C = QKV + (size_t)z * NX;
#pragma unroll
        for (int mr = 0; mr < 4; ++mr)
#pragma unroll
            for (int i = 0; i < 4; ++i) {
                const int rg = m0 + wm * 64 + mr * 16 + quad * 4 + i;
                C[(size_t)rg * D_MODEL + c] = (bf16)((acc[mr][nr][i] + bsv) * scale);
            }
    }
}

// ---------------------------------------------------------------------------
// Block-sparse flash attention, 64-key chunks, NO-MAX single-pass softmax
// (scores |s|<~8 so exp never overflows; masked entries written as exact 0;
// accumulation is order-free: O = sum p*V, l = sum p). R2 structure:
// K + V staged in LDS, register-pipelined prefetch issued right after the
// barrier. New vs R2: (a) K single-buffered (no post-QK^T consumer) ->
// LDS 46KB -> 36KB -> 4 blocks/CU, one extra uniform barrier after QK^T;
// (b) invalid key-groups skipped by wave-uniform branch (MFMA + exp + kpm),
// zeros written to Ps instead. Q arrives pre-scaled by 0.125. Output f32.
// XCD swizzle: blocks sharing (b,h) cluster on one XCD (K/V L2-resident).
// ---------------------------------------------------------------------------
__global__ __launch_bounds__(256, 4) void sparse_attn64(
    const bf16* __restrict__ Q, const bf16* __restrict__ Kv,
    const bf16* __restrict__ Vv, const float* __restrict__ kpm,
    float* __restrict__ out)
{
    // linear id -> (xcd k, j); pair = k*4 + (j&3); w descending in j.
    const int lid = blockIdx.x + 32 * (blockIdx.y + 16 * blockIdx.z);
    const int xk = lid & 7, j = lid >> 3;
    const int pair = xk * 4 + (j & 3);
    const int h = pair & 15, b = pair >> 4;
    const int w = 31 - (j >> 2);                  // longest windows first

    const int t = threadIdx.x, wavei = t >> 6, lane = t & 63;
    const int col = lane & 15, quad = lane >> 4;
    const int qb = 4 * w + wavei;

    __shared__ bf16 KbS[64 * 72];      // [kj][d]  stride 72, SINGLE buffer
    __shared__ bf16 VtS[2][64 * 72];   // [d][kj]  stride 72, double buffer
    __shared__ bf16 Ps[4][16 * 72];    // per-wave [qi][kj]

    const size_t qrow = ((size_t)(b * S_LEN + qb * 16 + col)) * D_MODEL + h * HD;
    const bf16x8 aq0 = *(const bf16x8*)(Q + qrow + quad * 8);
    const bf16x8 aq1 = *(const bf16x8*)(Q + qrow + 32 + quad * 8);

    f32x4 o[4] = {};
    float lacc[4] = {0.f, 0.f, 0.f, 0.f};

    const int nGlob = (w + 3) >> 2;
    const int niter = nGlob + 1;

    // K staging: thread = row srow (0..63), d-range sd16..+15
    const int srow = t >> 2, sd16 = (t & 3) << 4;
    const int sg = srow >> 4, sr = srow & 15;
    // V staging: thread = key pair (2p2, 2p2+1), d-range dg8..+7
    const int p2 = t & 31, dg8 = (t >> 5) << 3;
    const int key0 = 2 * p2, vg = key0 >> 4, vr = key0 & 15;

    // kb for (chunk it, group g); invalid globals clamp to kb=3 (skipped later)
    auto kb_of = [&](int it, int g) -> int {
        if (it >= nGlob) return 4 * w + g;
        const int jj = 4 * it + g;
        return (jj < w) ? (4 * jj + 3) : 3;
    };

    bf16x8 rk0, rk1, rv0, rv1;
    {   // prologue: load + stage chunk 0 (K single buf, V buf 0)
        const size_t krow = ((size_t)(b * S_LEN + kb_of(0, sg) * 16 + sr)) * D_MODEL + h * HD + sd16;
        rk0 = *(const bf16x8*)(Kv + krow);
        rk1 = *(const bf16x8*)(Kv + krow + 8);
        const size_t vrow = ((size_t)(b * S_LEN + kb_of(0, vg) * 16 + vr)) * D_MODEL + h * HD + dg8;
        rv0 = *(const bf16x8*)(Vv + vrow);
        rv1 = *(const bf16x8*)(Vv + vrow + D_MODEL);
        *(bf16x8*)(KbS + srow * 72 + sd16)     = rk0;
        *(bf16x8*)(KbS + srow * 72 + sd16 + 8) = rk1;
#pragma unroll
        for (int jj = 0; jj < 8; ++jj) {
            bf16 pr[2] = { rv0[jj], rv1[jj] };
            *(unsigned int*)(VtS[0] + (dg8 + jj) * 72 + key0) = *(unsigned int*)pr;
        }
    }

    for (int it = 0; it < niter; ++it) {
        __syncthreads();    // sync1: staging of chunk `it` visible to all waves
        const int cur = it & 1, nxt = cur ^ 1;
        const bool more = (it + 1 < niter);
        if (more) {   // prefetch chunk it+1 into registers (overlaps MFMAs)
            const size_t krow = ((size_t)(b * S_LEN + kb_of(it + 1, sg) * 16 + sr)) * D_MODEL + h * HD + sd16;
            rk0 = *(const bf16x8*)(Kv + krow);
            rk1 = *(const bf16x8*)(Kv + krow + 8);
            const size_t vrow = ((size_t)(b * S_LEN + kb_of(it + 1, vg) * 16 + vr)) * D_MODEL + h * HD + dg8;
            rv0 = *(const bf16x8*)(Vv + vrow);
            rv1 = *(const bf16x8*)(Vv + vrow + D_MODEL);
        }

        // ---- S = Q K^T over 64 keys; invalid groups skipped (wave-uniform) ----
        f32x4 s[4];
        float mval[4];
        bool  val[4];
#pragma unroll
        for (int g = 0; g < 4; ++g) {
            val[g] = (it == nGlob) ? (g <= wavei) : (4 * it + g < w);
            if (val[g]) {
                const int kb = kb_of(it, g);
                mval[g] = kpm[b * S_LEN + kb * 16 + col];
                f32x4 z = {};
                const bf16x8 bk0 = *(const bf16x8*)(KbS + (g * 16 + col) * 72 + quad * 8);
                const bf16x8 bk1 = *(const bf16x8*)(KbS + (g * 16 + col) * 72 + 32 + quad * 8);
                __builtin_amdgcn_s_setprio(1);
                z = __builtin_amdgcn_mfma_f32_16x16x32_bf16(aq0, bk0, z, 0, 0, 0);
                s[g] = __builtin_amdgcn_mfma_f32_16x16x32_bf16(aq1, bk1, z, 0, 0, 0);
                __builtin_amdgcn_s_setprio(0);
            }
        }

        __syncthreads();    // sync2: all waves done reading KbS
        if (more) {   // restage K(it+1) into the single buffer
            *(bf16x8*)(KbS + srow * 72 + sd16)     = rk0;
            *(bf16x8*)(KbS + srow * 72 + sd16 + 8) = rk1;
        }

        // ---- p = exp(s + mask); zeros for invalid groups (order-free sums) ----
#pragma unroll
        for (int g = 0; g < 4; ++g) {
            if (val[g]) {
#pragma unroll
                for (int i = 0; i < 4; ++i) {
                    const float pv = __expf(s[g][i] + mval[g]);
                    lacc[i] += pv;
                    Ps[wavei][(quad * 4 + i) * 72 + g * 16 + col] = (bf16)pv;
                }
            } else {
#pragma unroll
                for (int i = 0; i < 4; ++i)
                    Ps[wavei][(quad * 4 + i) * 72 + g * 16 + col] = (bf16)0.0f;
            }
        }

        // ---- O += P V : full K-depth 64 (wave-synchronous Ps round-trip) ----
        const bf16* Vt = VtS[cur];
        const bf16x8 aP0 = *(const bf16x8*)(Ps[wavei] + col * 72 + quad * 8);
        const bf16x8 aP1 = *(const bf16x8*)(Ps[wavei] + col * 72 + 32 + quad * 8);
        __builtin_amdgcn_s_setprio(1);
#pragma unroll
        for (int nt = 0; nt < 4; ++nt) {
            const bf16x8 b0 = *(const bf16x8*)(Vt + (nt * 16 + col) * 72 + quad * 8);
            const bf16x8 b1 = *(const bf16x8*)(Vt + (nt * 16 + col) * 72 + 32 + quad * 8);
            o[nt] = __builtin_amdgcn_mfma_f32_16x16x32_bf16(aP0, b0, o[nt], 0, 0, 0);
            o[nt] = __builtin_amdgcn_mfma_f32_16x16x32_bf16(aP1, b1, o[nt], 0, 0, 0);
        }
        __builtin_amdgcn_s_setprio(0);

        if (more) {   // stage V(it+1) into the other buffer (no barrier needed)
#pragma unroll
            for (int jj = 0; jj < 8; ++jj) {
                bf16 pr[2] = { rv0[jj], rv1[jj] };
                *(unsigned int*)(VtS[nxt] + (dg8 + jj) * 72 + key0) = *(unsigned int*)pr;
            }
        }
    }

    // ---- deferred row-sum reduction (once per block) ----
#pragma unroll
    for (int i = 0; i < 4; ++i) {
        float rs = lacc[i];
        rs += __shfl_xor(rs, 1);
        rs += __shfl_xor(rs, 2);
        rs += __shfl_xor(rs, 4);
        rs += __shfl_xor(rs, 8);
        const float inv = 1.0f / rs;
        const int rg = b * S_LEN + qb * 16 + quad * 4 + i;
#pragma unroll
        for (int nt = 0; nt < 4; ++nt)
            out[(size_t)rg * D_MODEL + h * HD + nt * 16 + col] = o[nt][i] * inv;
    }
}

// ---------------------------------------------------------------------------
extern "C" void kernel_launch(void* const* d_in, const int* in_sizes, int n_in,
                              void* d_out, int out_size, void* d_ws, size_t ws_size,
                              hipStream_t stream)
{
    const float* x = nullptr; const float* kpm = nullptr;
    const float* Wp[3] = {nullptr, nullptr, nullptr};
    const float* bp[3] = {nullptr, nullptr, nullptr};
    int wn = 0, bn = 0;
    for (int i = 0; i < n_in; ++i) {
        const float* p = (const float*)d_in[i];
        const long s = in_sizes[i];
        if (s == (long)NX)            x = p;
        else if (s == BATCH * S_LEN)  kpm = p;
        else if (s == D_MODEL * D_MODEL && wn < 3) Wp[wn++] = p;
        else if (s == D_MODEL && bn < 3)           bp[bn++] = p;
    }

    // ws (24 MB, proven safe): [Q | K | V] bf16.
    bf16* Qb = (bf16*)d_ws;
    bf16* Kb = Qb + NX;
    bf16* Vb = Kb + NX;
    // d_out (16 MB f32) doubles as pre-attention scratch: [Xb 8MB | Wt 6MB].
    bf16* Xb = (bf16*)d_out;
    bf16* Wt = Xb + NX;
    float* outp = (float*)d_out;

    static bool attr_done = false;
    if (!attr_done) {
        (void)hipFuncSetAttribute(reinterpret_cast<const void*>(gemm_qkv_dp),
                                  hipFuncAttributeMaxDynamicSharedMemorySize, 114688);
        attr_done = true;
    }

    prep<<<2816, 256, 0, stream>>>(x, Xb, Wp[0], Wp[1], Wp[2], Wt);

    // 256x192 tiles, XCD-rect swizzle: 256 blocks = 1 per CU. 112KB LDS.
    gemm_qkv_dp<<<dim3(256), 512, 114688, stream>>>(
        Xb, Wt, bp[0], bp[1], bp[2], Qb);

    sparse_attn64<<<dim3(S_LEN / 64, NH, BATCH), 256, 0, stream>>>(
        Qb, Kb, Vb, kpm, outp);
}